// Round 1
// baseline (385.484 us; speedup 1.0000x reference)
//
#include <hip/hip_runtime.h>

#define GXc 96
#define GYc 96
#define RFc 24
#define Bc 8
#define Nc (GXc * GYc)          // 9216
#define Hc (GXc - 1 + RFc)      // 119
#define IN_IMG (Hc * Hc)        // 14161
#define RF2 (RFc * RFc)         // 576
#define GAMMA 0.9f

#define ROWS 4                  // output rows per wave
#define WAVES_PER_BLOCK 4
#define ROWS_PER_BLOCK (ROWS * WAVES_PER_BLOCK)   // 16
#define NBLOCKS (Nc / ROWS_PER_BLOCK)             // 576
#define KITERS (Nc / 32)                          // 288 (32 k-elems per wave-iter)

__global__ __launch_bounds__(256) void cortex_fused_kernel(
    const float* __restrict__ input,   // (B, 119, 119)
    const float* __restrict__ prev,    // (B, N)
    const float* __restrict__ aw,      // (96, 96, 24, 24) = (N, 576)
    const float* __restrict__ We,      // (N, N)
    const float* __restrict__ Wi,      // (N, N)
    float* __restrict__ out)           // (B, N)
{
    const int tid  = threadIdx.x;
    const int wave = tid >> 6;
    const int lane = tid & 63;
    const int b    = lane >> 3;   // batch index, 0..7
    const int s    = lane & 7;    // k-sublane within batch group, 0..7
    const int rowbase = blockIdx.x * ROWS_PER_BLOCK + wave * ROWS;

    // ---------------- afferent (local RF conv), fully in registers ----------
    float aff[ROWS];
    const float* inb = input + b * IN_IMG;
#pragma unroll
    for (int r = 0; r < ROWS; ++r) {
        const int n  = rowbase + r;
        const int gi = n / GYc;
        const int gj = n - gi * GYc;
        const float* awn  = aw + (size_t)n * RF2;
        const float* inbo = inb + gi * Hc + gj;
        float a = 0.f;
        for (int t = 0; t < RF2 / 8; ++t) {     // 72 iters, lane handles hw = t*8+s
            const int hw = t * 8 + s;
            const int h  = hw / RFc;
            const int w  = hw - h * RFc;
            a += awn[hw] * inbo[h * Hc + w];
        }
        // reduce over the 8 k-sublanes of this batch group
        a += __shfl_xor(a, 1);
        a += __shfl_xor(a, 2);
        a += __shfl_xor(a, 4);
        aff[r] = a;
    }

    // ---------------- lateral: prev @ (We - Wi)^T, streamed ----------------
    float acc[ROWS];
#pragma unroll
    for (int r = 0; r < ROWS; ++r) acc[r] = 0.f;

    const float* pb = prev + b * Nc;
    for (int j = 0; j < KITERS; ++j) {
        const int k0 = j * 32 + s * 4;
        const float4 p4 = *(const float4*)(pb + k0);
#pragma unroll
        for (int r = 0; r < ROWS; ++r) {
            const size_t rowoff = (size_t)(rowbase + r) * Nc + k0;
            const float4 we4 = *(const float4*)(We + rowoff);
            const float4 wi4 = *(const float4*)(Wi + rowoff);
            acc[r] += (we4.x - wi4.x) * p4.x
                    + (we4.y - wi4.y) * p4.y
                    + (we4.z - wi4.z) * p4.z
                    + (we4.w - wi4.w) * p4.w;
        }
    }

    // ---------------- reduce + epilogue ------------------------------------
#pragma unroll
    for (int r = 0; r < ROWS; ++r) {
        float a = acc[r];
        a += __shfl_xor(a, 1);
        a += __shfl_xor(a, 2);
        a += __shfl_xor(a, 4);
        const float tot = aff[r] + GAMMA * a;
        if (s == 0) {
            const int n = rowbase + r;
            out[b * Nc + n] = tot > 0.f ? tot : 0.f;
        }
    }
}

extern "C" void kernel_launch(void* const* d_in, const int* in_sizes, int n_in,
                              void* d_out, int out_size, void* d_ws, size_t ws_size,
                              hipStream_t stream) {
    const float* input = (const float*)d_in[0];
    const float* prev  = (const float*)d_in[1];
    const float* aw    = (const float*)d_in[2];
    const float* We    = (const float*)d_in[3];
    const float* Wi    = (const float*)d_in[4];
    // d_in[5], d_in[6] are rf_x / rf_y == arange(96): identity, folded into indexing.
    float* out = (float*)d_out;

    cortex_fused_kernel<<<NBLOCKS, 256, 0, stream>>>(input, prev, aw, We, Wi, out);
}

// Round 2
// 183.745 us; speedup vs baseline: 2.0979x; 2.0979x over previous
//
#include <hip/hip_runtime.h>

#define GXc 96
#define GYc 96
#define RFc 24
#define Bc 8
#define Nc (GXc * GYc)          // 9216
#define Hc (GXc - 1 + RFc)      // 119
#define IN_IMG (Hc * Hc)        // 14161
#define RF2 (RFc * RFc)         // 576
#define GAMMA 0.9f
#define INV_GAMMA (1.0f / 0.9f)

#define ROWS 4                  // output rows per wave
#define WAVES_PER_BLOCK 4
#define ROWS_PER_BLOCK (ROWS * WAVES_PER_BLOCK)   // 16
#define NBLOCKS (Nc / ROWS_PER_BLOCK)             // 576
#define KITERS (Nc / 256)                         // 36 (256 k-elems per wave-iter)

__global__ __launch_bounds__(256) void cortex_fused_kernel(
    const float* __restrict__ input,   // (B, 119, 119)
    const float* __restrict__ prev,    // (B, N)
    const float* __restrict__ aw,      // (96, 96, 24, 24) = (N, 576)
    const float* __restrict__ We,      // (N, N)
    const float* __restrict__ Wi,      // (N, N)
    float* __restrict__ out)           // (B, N)
{
    const int tid  = threadIdx.x;
    const int wave = tid >> 6;
    const int lane = tid & 63;
    const int rowbase = blockIdx.x * ROWS_PER_BLOCK + wave * ROWS;

    // acc[r][b] accumulates (afferent/GAMMA) + prev@(We-Wi)^T partials.
    float acc[ROWS][Bc];
#pragma unroll
    for (int r = 0; r < ROWS; ++r)
#pragma unroll
        for (int b = 0; b < Bc; ++b) acc[r][b] = 0.f;

    // ---------------- afferent (local RF conv), all-lane k layout ----------
    // lane handles rf-elements hw = t*64 + lane; pre-scaled by 1/GAMMA so the
    // single epilogue multiply by GAMMA restores it.
#pragma unroll
    for (int r = 0; r < ROWS; ++r) {
        const int n  = rowbase + r;
        const int gi = n / GYc;
        const int gj = n - gi * GYc;
        const float* awn = aw + (size_t)n * RF2;
        const int base = gi * Hc + gj;
#pragma unroll
        for (int t = 0; t < RF2 / 64; ++t) {   // 9 iters
            const int hw = t * 64 + lane;
            const int h  = hw / RFc;
            const int w  = hw - h * RFc;
            const float av  = awn[hw] * INV_GAMMA;
            const int  off  = base + h * Hc + w;
#pragma unroll
            for (int b = 0; b < Bc; ++b)
                acc[r][b] += input[b * IN_IMG + off] * av;
        }
    }

    // ---------------- lateral: prev @ (We - Wi)^T, full-wave coalesced -----
    const int koff = lane * 4;
    for (int j = 0; j < KITERS; ++j) {
        const int k0 = j * 256 + koff;

        // issue all W loads first (8 x 1KB coalesced segments in flight)
        float4 we4[ROWS], wi4[ROWS];
#pragma unroll
        for (int r = 0; r < ROWS; ++r) {
            const size_t ro = (size_t)(rowbase + r) * Nc + k0;
            we4[r] = *(const float4*)(We + ro);
            wi4[r] = *(const float4*)(Wi + ro);
        }
        // prev tiles (L2-resident, coalesced per-b)
        float4 p[Bc];
#pragma unroll
        for (int b = 0; b < Bc; ++b)
            p[b] = *(const float4*)(prev + b * Nc + k0);

#pragma unroll
        for (int r = 0; r < ROWS; ++r) {
            const float4 w4 = make_float4(we4[r].x - wi4[r].x,
                                          we4[r].y - wi4[r].y,
                                          we4[r].z - wi4[r].z,
                                          we4[r].w - wi4[r].w);
#pragma unroll
            for (int b = 0; b < Bc; ++b)
                acc[r][b] += w4.x * p[b].x + w4.y * p[b].y
                           + w4.z * p[b].z + w4.w * p[b].w;
        }
    }

    // ---------------- full-wave butterfly reduce + epilogue ----------------
#pragma unroll
    for (int r = 0; r < ROWS; ++r)
#pragma unroll
        for (int b = 0; b < Bc; ++b) {
            float v = acc[r][b];
            v += __shfl_xor(v, 1);
            v += __shfl_xor(v, 2);
            v += __shfl_xor(v, 4);
            v += __shfl_xor(v, 8);
            v += __shfl_xor(v, 16);
            v += __shfl_xor(v, 32);
            acc[r][b] = v;
        }

#pragma unroll
    for (int r = 0; r < ROWS; ++r)
#pragma unroll
        for (int b = 0; b < Bc; ++b)
            if (lane == b * 8 + r) {
                const float tot = GAMMA * acc[r][b];
                out[b * Nc + rowbase + r] = tot > 0.f ? tot : 0.f;
            }
}

extern "C" void kernel_launch(void* const* d_in, const int* in_sizes, int n_in,
                              void* d_out, int out_size, void* d_ws, size_t ws_size,
                              hipStream_t stream) {
    const float* input = (const float*)d_in[0];
    const float* prev  = (const float*)d_in[1];
    const float* aw    = (const float*)d_in[2];
    const float* We    = (const float*)d_in[3];
    const float* Wi    = (const float*)d_in[4];
    // d_in[5], d_in[6] are rf_x / rf_y == arange(96): identity, folded into indexing.
    float* out = (float*)d_out;

    cortex_fused_kernel<<<NBLOCKS, 256, 0, stream>>>(input, prev, aw, We, Wi, out);
}